// Round 12
// baseline (259.252 us; speedup 1.0000x reference)
//
#include <hip/hip_runtime.h>
#include <math.h>

#define EMBED_DIM 64
#define NUM_EXPERTS 4
#define THREADS 128                 // 2 INDEPENDENT waves per block
#define TOKS 32                     // tokens per tile (8 KB)
#define CH 512                      // 32 tokens * 16 float4 chunks
#define NBLOCKS 1280                // persistent: 5 blocks/CU, 10 waves/CU

// Persistent waves + REG-STAGED depth-2 pipeline. Theory: all prior
// structures phase-lock (stage-spike then ~1100cy zero-demand compute
// valley); here each wave issues the NEXT tile's 8 coalesced loads into a
// named register set BEFORE processing the current tile, so 8 KB/wave stays
// outstanding through every compute phase — HBM demand never idles.
// Unlike R8 (global_load_lds + compiler-forced vmcnt(0) drain), reg-staging
// lets the compiler's per-register vmcnt staircase wait ONLY on the
// current tile's loads while next-tile loads remain in flight.
// Named rA/rB sets with explicit A/B phase unroll (no dynamic reg indexing);
// two 8 KB LDS buffers per wave remove LDS WAR hazards.
//
// Arithmetic is bit-identical to the passing kernels: strictly sequential
// f32 mul-then-add chain per logit (no FMA contraction; pragma disables
// -ffp-contract=fast), matching numpy einsum's sum-of-products order.
// XOR chunk swizzle at LDS write + same XOR at read; global loads linear.
__global__ __launch_bounds__(THREADS) void gate_kernel(
    const float* __restrict__ x,
    const float* __restrict__ W,
    float* __restrict__ wout,     // [n,4] dense routing weights
    float* __restrict__ iout,     // [n,2] top-k indices, stored as float
    int n)
{
#pragma clang fp contract(off)
    __shared__ float4 lds[2 * 2 * CH];   // [wave][parity][CH]

    const int lane = threadIdx.x & 63;
    const int wid  = threadIdx.x >> 6;
    const int gw   = blockIdx.x * 2 + wid;      // global wave id
    const int NW   = NBLOCKS * 2;               // 2560 worker waves
    const int ntiles = n / TOKS;                // 65536

    const float4* x4 = reinterpret_cast<const float4*>(x);
    const float4* W4 = reinterpret_cast<const float4*>(W);
    float4* buf0 = &lds[(wid * 2 + 0) * CH];
    float4* buf1 = &lds[(wid * 2 + 1) * CH];

    float4 rA[8], rB[8];

    auto LOAD = [&](float4 (&r)[8], int tile) {
        const size_t tc = (size_t)tile * CH;
        #pragma unroll
        for (int i = 0; i < 8; ++i) r[i] = x4[tc + i * 64 + lane];
    };

    auto PROCESS = [&](const float4 (&r)[8], int tile, float4* buf) {
        // Swizzled LDS writes: chunk G=(tk<<4)|c -> (tk<<4)|(c^(tk&7)).
        #pragma unroll
        for (int i = 0; i < 8; ++i) {
            const int G  = i * 64 + lane;
            const int tk = G >> 4;
            const int c  = G & 15;
            buf[(tk << 4) | (c ^ (tk & 7))] = r[i];
        }
        if (lane < TOKS) {
            float s0 = 0.0f, s1 = 0.0f, s2 = 0.0f, s3 = 0.0f;
            #pragma unroll
            for (int j = 0; j < 16; ++j) {
                const float4 xv = buf[(lane << 4) | (j ^ (lane & 7))];
                const float4 a = W4[ 0 + j];
                const float4 b = W4[16 + j];
                const float4 c = W4[32 + j];
                const float4 d = W4[48 + j];
                // strict d-order, mul rounded then add rounded:
                s0 = s0 + xv.x * a.x; s0 = s0 + xv.y * a.y;
                s0 = s0 + xv.z * a.z; s0 = s0 + xv.w * a.w;
                s1 = s1 + xv.x * b.x; s1 = s1 + xv.y * b.y;
                s1 = s1 + xv.z * b.z; s1 = s1 + xv.w * b.w;
                s2 = s2 + xv.x * c.x; s2 = s2 + xv.y * c.y;
                s2 = s2 + xv.z * c.z; s2 = s2 + xv.w * c.w;
                s3 = s3 + xv.x * d.x; s3 = s3 + xv.y * d.y;
                s3 = s3 + xv.z * d.z; s3 = s3 + xv.w * d.w;
            }
            // top-1: strict > -> ties to LOWER index (lax.top_k).
            int   i1 = 0;  float v1 = s0;
            if (s1 > v1) { v1 = s1; i1 = 1; }
            if (s2 > v1) { v1 = s2; i1 = 2; }
            if (s3 > v1) { v1 = s3; i1 = 3; }
            int   i2 = -1; float v2 = -INFINITY;
            if (i1 != 0 && s0 > v2) { v2 = s0; i2 = 0; }
            if (i1 != 1 && s1 > v2) { v2 = s1; i2 = 1; }
            if (i1 != 2 && s2 > v2) { v2 = s2; i2 = 2; }
            if (i1 != 3 && s3 > v2) { v2 = s3; i2 = 3; }

            const float e2  = expf(v2 - v1);
            const float den = 1.0f + e2;
            const float p1  = 1.0f / den;
            const float p2  = e2 / den;

            const int tok = tile * TOKS + lane;
            float4 wv;
            wv.x = (i1 == 0) ? p1 : ((i2 == 0) ? p2 : 0.0f);
            wv.y = (i1 == 1) ? p1 : ((i2 == 1) ? p2 : 0.0f);
            wv.z = (i1 == 2) ? p1 : ((i2 == 2) ? p2 : 0.0f);
            wv.w = (i1 == 3) ? p1 : ((i2 == 3) ? p2 : 0.0f);
            reinterpret_cast<float4*>(wout)[tok] = wv;
            float2 iv;
            iv.x = (float)i1;
            iv.y = (float)i2;
            reinterpret_cast<float2*>(iout)[tok] = iv;
        }
    };

    int tA = gw;
    if (tA >= ntiles) return;
    LOAD(rA, tA);

    for (;;) {
        const int tB = tA + NW;
        if (tB < ntiles) {
            LOAD(rB, tB);                         // B in flight during A
            __builtin_amdgcn_sched_barrier(0);    // pin issue order
            PROCESS(rA, tA, buf0);
            const int tA2 = tB + NW;
            if (tA2 < ntiles) {
                LOAD(rA, tA2);                    // A' in flight during B
                __builtin_amdgcn_sched_barrier(0);
                PROCESS(rB, tB, buf1);
                tA = tA2;
                continue;
            } else {
                PROCESS(rB, tB, buf1);
                break;
            }
        } else {
            PROCESS(rA, tA, buf0);
            break;
        }
    }
}

extern "C" void kernel_launch(void* const* d_in, const int* in_sizes, int n_in,
                              void* d_out, int out_size, void* d_ws, size_t ws_size,
                              hipStream_t stream) {
    const float* x = (const float*)d_in[0];
    const float* W = (const float*)d_in[1];
    const int n = in_sizes[0] / EMBED_DIM;   // 2097152

    float* wout = (float*)d_out;                    // n*4 floats
    float* iout = wout + (size_t)n * NUM_EXPERTS;   // n*2 indices stored as float

    hipLaunchKernelGGL(gate_kernel, dim3(NBLOCKS), dim3(THREADS), 0, stream,
                       x, W, wout, iout, n);
}

// Round 14
// 99.032 us; speedup vs baseline: 2.6179x; 2.6179x over previous
//
#include <hip/hip_runtime.h>
#include <math.h>

#define EMBED_DIM 64
#define NUM_EXPERTS 4
#define THREADS 128                 // 2 INDEPENDENT waves per block
#define TILE_CHUNKS 1024            // 64 tokens * 16 float4 = 16 KB per wave
#define NBLOCKS 16384               // short-lived blocks: churn pipelining

typedef float  f32x4 __attribute__((ext_vector_type(4)));
typedef float  f32x2 __attribute__((ext_vector_type(2)));

// Best-known structure (R10: churn blocks, independent waves, reg-staged
// LDS exchange, no barrier) + NONTEMPORAL loads/stores (via native clang
// vector types — HIP_vector_type structs are rejected by the builtin).
// The stream has zero reuse, so the nt cache policy skips L2/LLC line
// retention for the 537MB read + 50MB write streams — probing whether
// cache-fill overhead is the residual 25% vs the fills' 6.7-6.9 TB/s.
//
// Arithmetic is bit-identical to the passing kernels: strictly sequential
// f32 mul-then-add chain per logit (no FMA contraction; pragma disables
// -ffp-contract=fast), matching numpy einsum's sum-of-products order.
// XOR chunk swizzle at the LDS write and the same XOR at the read ->
// bank-conflict-free both ends; global loads purely linear.
__global__ __launch_bounds__(THREADS) void gate_kernel(
    const float* __restrict__ x,
    const float* __restrict__ W,
    float* __restrict__ wout,     // [n,4] dense routing weights
    float* __restrict__ iout,     // [n,2] top-k indices, stored as float
    int n)
{
#pragma clang fp contract(off)
    __shared__ float4 lds[2 * TILE_CHUNKS];   // one 16KB tile per wave

    const int lane = threadIdx.x & 63;
    const int wid  = threadIdx.x >> 6;               // wave in block: 0/1
    const int tile = blockIdx.x * 2 + wid;           // this wave's tile
    float4* tilebuf = &lds[wid * TILE_CHUNKS];

    const f32x4* x4 = reinterpret_cast<const f32x4*>(x);
    const float4* W4 = reinterpret_cast<const float4*>(W);

    // 16 linear, fully-coalesced nontemporal loads: chunk G = i*64 + lane.
    const size_t tileChunk = (size_t)tile * TILE_CHUNKS;
    f32x4 r[16];
    #pragma unroll
    for (int i = 0; i < 16; ++i) {
        r[i] = __builtin_nontemporal_load(&x4[tileChunk + i * 64 + lane]);
    }

    // Swizzled LDS writes: chunk G=(tk<<4)|c -> (tk<<4)|(c^(tk&7)).
    // Each instruction writes a contiguous 1KB span -> conflict-free.
    #pragma unroll
    for (int i = 0; i < 16; ++i) {
        const int G  = i * 64 + lane;
        const int tk = G >> 4;
        const int c  = G & 15;
        float4 v;
        v.x = r[i].x; v.y = r[i].y; v.z = r[i].z; v.w = r[i].w;
        tilebuf[(tk << 4) | (c ^ (tk & 7))] = v;
    }
    __builtin_amdgcn_sched_barrier(0);   // keep reads below the writes

    float s0 = 0.0f, s1 = 0.0f, s2 = 0.0f, s3 = 0.0f;
    #pragma unroll
    for (int j = 0; j < 16; ++j) {
        const float4 xv = tilebuf[(lane << 4) | (j ^ (lane & 7))];
        const float4 a = W4[ 0 + j];
        const float4 b = W4[16 + j];
        const float4 c = W4[32 + j];
        const float4 d = W4[48 + j];
        // strict d-order, mul rounded then add rounded (no contraction):
        s0 = s0 + xv.x * a.x; s0 = s0 + xv.y * a.y;
        s0 = s0 + xv.z * a.z; s0 = s0 + xv.w * a.w;
        s1 = s1 + xv.x * b.x; s1 = s1 + xv.y * b.y;
        s1 = s1 + xv.z * b.z; s1 = s1 + xv.w * b.w;
        s2 = s2 + xv.x * c.x; s2 = s2 + xv.y * c.y;
        s2 = s2 + xv.z * c.z; s2 = s2 + xv.w * c.w;
        s3 = s3 + xv.x * d.x; s3 = s3 + xv.y * d.y;
        s3 = s3 + xv.z * d.z; s3 = s3 + xv.w * d.w;
    }

    // top-1: strict > -> ties to LOWER index (lax.top_k semantics).
    int   i1 = 0;  float v1 = s0;
    if (s1 > v1) { v1 = s1; i1 = 1; }
    if (s2 > v1) { v1 = s2; i1 = 2; }
    if (s3 > v1) { v1 = s3; i1 = 3; }
    int   i2 = -1; float v2 = -INFINITY;
    if (i1 != 0 && s0 > v2) { v2 = s0; i2 = 0; }
    if (i1 != 1 && s1 > v2) { v2 = s1; i2 = 1; }
    if (i1 != 2 && s2 > v2) { v2 = s2; i2 = 2; }
    if (i1 != 3 && s3 > v2) { v2 = s3; i2 = 3; }

    const float e2  = expf(v2 - v1);
    const float den = 1.0f + e2;
    const float p1  = 1.0f / den;
    const float p2  = e2 / den;

    const int tok = tile * 64 + lane;

    f32x4 wv;
    wv.x = (i1 == 0) ? p1 : ((i2 == 0) ? p2 : 0.0f);
    wv.y = (i1 == 1) ? p1 : ((i2 == 1) ? p2 : 0.0f);
    wv.z = (i1 == 2) ? p1 : ((i2 == 2) ? p2 : 0.0f);
    wv.w = (i1 == 3) ? p1 : ((i2 == 3) ? p2 : 0.0f);
    __builtin_nontemporal_store(wv, &reinterpret_cast<f32x4*>(wout)[tok]);

    f32x2 iv;
    iv.x = (float)i1;
    iv.y = (float)i2;
    __builtin_nontemporal_store(iv, &reinterpret_cast<f32x2*>(iout)[tok]);
}

extern "C" void kernel_launch(void* const* d_in, const int* in_sizes, int n_in,
                              void* d_out, int out_size, void* d_ws, size_t ws_size,
                              hipStream_t stream) {
    const float* x = (const float*)d_in[0];
    const float* W = (const float*)d_in[1];
    const int n = in_sizes[0] / EMBED_DIM;   // 2097152

    float* wout = (float*)d_out;                    // n*4 floats
    float* iout = wout + (size_t)n * NUM_EXPERTS;   // n*2 indices stored as float

    hipLaunchKernelGGL(gate_kernel, dim3(NBLOCKS), dim3(THREADS), 0, stream,
                       x, W, wout, iout, n);
}

// Round 15
// 98.934 us; speedup vs baseline: 2.6204x; 1.0010x over previous
//
#include <hip/hip_runtime.h>
#include <math.h>

#define EMBED_DIM 64
#define NUM_EXPERTS 4
#define THREADS 128                 // 2 INDEPENDENT waves per block
#define TOKS_PER_WAVE 32            // 32 tokens = 8 KB per wave
#define TILE_CHUNKS 512             // 32 tokens * 16 float4
#define NBLOCKS 32768               // n / 64 tokens per block

typedef float  f32x4 __attribute__((ext_vector_type(4)));
typedef float  f32x2 __attribute__((ext_vector_type(2)));

// R14 (nontemporal, churn blocks, independent waves, reg-staged LDS) +
// R11's half-tile/double-occupancy (8KB/wave -> 16KB/block -> 10 blocks/CU
// = 20 waves/CU). Pre-nt this was neutral (cache-fill path was the cap);
// post-nt the limiter may have shifted to demand smoothness, where 2x
// waves/CU can fill scheduling valleys. Staging uses all 64 lanes (8
// coalesced 1KB nt loads); compute uses lanes 0-31 (one token per lane).
//
// Arithmetic is bit-identical to the passing kernels: strictly sequential
// f32 mul-then-add chain per logit (no FMA contraction; pragma disables
// -ffp-contract=fast), matching numpy einsum's sum-of-products order.
// XOR chunk swizzle at the LDS write and the same XOR at the read ->
// bank-conflict-free both ends; global loads purely linear.
__global__ __launch_bounds__(THREADS) void gate_kernel(
    const float* __restrict__ x,
    const float* __restrict__ W,
    float* __restrict__ wout,     // [n,4] dense routing weights
    float* __restrict__ iout,     // [n,2] top-k indices, stored as float
    int n)
{
#pragma clang fp contract(off)
    __shared__ float4 lds[2 * TILE_CHUNKS];   // one 8KB tile per wave

    const int lane = threadIdx.x & 63;
    const int wid  = threadIdx.x >> 6;               // wave in block: 0/1
    const int tile = blockIdx.x * 2 + wid;           // this wave's tile
    float4* tilebuf = &lds[wid * TILE_CHUNKS];

    const f32x4* x4 = reinterpret_cast<const f32x4*>(x);
    const float4* W4 = reinterpret_cast<const float4*>(W);

    // 8 linear, fully-coalesced nontemporal loads: chunk G = i*64 + lane.
    const size_t tileChunk = (size_t)tile * TILE_CHUNKS;
    f32x4 r[8];
    #pragma unroll
    for (int i = 0; i < 8; ++i) {
        r[i] = __builtin_nontemporal_load(&x4[tileChunk + i * 64 + lane]);
    }

    // Swizzled LDS writes: chunk G=(tk<<4)|c -> (tk<<4)|(c^(tk&7)).
    // Each instruction writes a contiguous 1KB span -> conflict-free.
    #pragma unroll
    for (int i = 0; i < 8; ++i) {
        const int G  = i * 64 + lane;
        const int tk = G >> 4;
        const int c  = G & 15;
        float4 v;
        v.x = r[i].x; v.y = r[i].y; v.z = r[i].z; v.w = r[i].w;
        tilebuf[(tk << 4) | (c ^ (tk & 7))] = v;
    }
    __builtin_amdgcn_sched_barrier(0);   // keep reads below the writes

    if (lane < TOKS_PER_WAVE) {
        float s0 = 0.0f, s1 = 0.0f, s2 = 0.0f, s3 = 0.0f;
        #pragma unroll
        for (int j = 0; j < 16; ++j) {
            const float4 xv = tilebuf[(lane << 4) | (j ^ (lane & 7))];
            const float4 a = W4[ 0 + j];
            const float4 b = W4[16 + j];
            const float4 c = W4[32 + j];
            const float4 d = W4[48 + j];
            // strict d-order, mul rounded then add rounded (no contraction):
            s0 = s0 + xv.x * a.x; s0 = s0 + xv.y * a.y;
            s0 = s0 + xv.z * a.z; s0 = s0 + xv.w * a.w;
            s1 = s1 + xv.x * b.x; s1 = s1 + xv.y * b.y;
            s1 = s1 + xv.z * b.z; s1 = s1 + xv.w * b.w;
            s2 = s2 + xv.x * c.x; s2 = s2 + xv.y * c.y;
            s2 = s2 + xv.z * c.z; s2 = s2 + xv.w * c.w;
            s3 = s3 + xv.x * d.x; s3 = s3 + xv.y * d.y;
            s3 = s3 + xv.z * d.z; s3 = s3 + xv.w * d.w;
        }

        // top-1: strict > -> ties to LOWER index (lax.top_k semantics).
        int   i1 = 0;  float v1 = s0;
        if (s1 > v1) { v1 = s1; i1 = 1; }
        if (s2 > v1) { v1 = s2; i1 = 2; }
        if (s3 > v1) { v1 = s3; i1 = 3; }
        int   i2 = -1; float v2 = -INFINITY;
        if (i1 != 0 && s0 > v2) { v2 = s0; i2 = 0; }
        if (i1 != 1 && s1 > v2) { v2 = s1; i2 = 1; }
        if (i1 != 2 && s2 > v2) { v2 = s2; i2 = 2; }
        if (i1 != 3 && s3 > v2) { v2 = s3; i2 = 3; }

        const float e2  = expf(v2 - v1);
        const float den = 1.0f + e2;
        const float p1  = 1.0f / den;
        const float p2  = e2 / den;

        const int tok = tile * TOKS_PER_WAVE + lane;

        f32x4 wv;
        wv.x = (i1 == 0) ? p1 : ((i2 == 0) ? p2 : 0.0f);
        wv.y = (i1 == 1) ? p1 : ((i2 == 1) ? p2 : 0.0f);
        wv.z = (i1 == 2) ? p1 : ((i2 == 2) ? p2 : 0.0f);
        wv.w = (i1 == 3) ? p1 : ((i2 == 3) ? p2 : 0.0f);
        __builtin_nontemporal_store(wv, &reinterpret_cast<f32x4*>(wout)[tok]);

        f32x2 iv;
        iv.x = (float)i1;
        iv.y = (float)i2;
        __builtin_nontemporal_store(iv, &reinterpret_cast<f32x2*>(iout)[tok]);
    }
}

extern "C" void kernel_launch(void* const* d_in, const int* in_sizes, int n_in,
                              void* d_out, int out_size, void* d_ws, size_t ws_size,
                              hipStream_t stream) {
    const float* x = (const float*)d_in[0];
    const float* W = (const float*)d_in[1];
    const int n = in_sizes[0] / EMBED_DIM;   // 2097152

    float* wout = (float*)d_out;                    // n*4 floats
    float* iout = wout + (size_t)n * NUM_EXPERTS;   // n*2 indices stored as float

    hipLaunchKernelGGL(gate_kernel, dim3(NBLOCKS), dim3(THREADS), 0, stream,
                       x, W, wout, iout, n);
}